// Round 2
// baseline (340.488 us; speedup 1.0000x reference)
//
#include <hip/hip_runtime.h>

#define T_DIM 1024
#define B_DIM 16384
#define GAMMA 0.99f

// 1023 scan rows (t = 1022 .. 0) in 128 groups of 8 slots, pipelined 4 groups
// deep with named register buffers (static indexing only). Group 127 slot 7
// is t = -1 -> handled by dedicated guarded "_last" variants; all other
// groups are branch-free.
constexpr int U = 8;

__global__ __launch_bounds__(64, 1)
void vtrace_scan_kernel(const float* __restrict__ v,
                        const float* __restrict__ rew,
                        const float* __restrict__ tlp,
                        const float* __restrict__ blp,
                        const float* __restrict__ rho_p,
                        const float* __restrict__ cis_p,
                        float* __restrict__ out_v,     // (T-1) x B
                        float* __restrict__ out_rho)   // T x B
{
    const int c = blockIdx.x * 64 + threadIdx.x;   // column; coalesced across lanes
    const float rho_clip = *rho_p;
    const float cis_clip = *cis_p;

    // Row T-1: rhos only; seeds carry and v_next.
    {
        const int idx = (T_DIM - 1) * B_DIM + c;
        float iw = expf(tlp[idx] - blp[idx]);
        out_rho[idx] = fminf(rho_clip, iw);
    }
    float v_next = v[(T_DIM - 1) * B_DIM + c];
    float carry  = v_next;

    // ---- software-pipelined load buffers ----
    float b0r[U], b0t[U], b0b[U], b0v[U];
    float b1r[U], b1t[U], b1b[U], b1v[U];
    float b2r[U], b2t[U], b2b[U], b2v[U];
    float b3r[U], b3t[U], b3b[U], b3v[U];

    auto load_group = [&](int g, float (&br)[U], float (&bt)[U],
                          float (&bb)[U], float (&bv)[U]) {
        const int base = (T_DIM - 2) - g * U;      // t for u=0
#pragma unroll
        for (int u = 0; u < U; ++u) {
            const int idx = (base - u) * B_DIM + c;
            br[u] = rew[idx];
            bt[u] = tlp[idx];
            bb[u] = blp[idx];
            bv[u] = v[idx];
        }
    };

    auto compute_group = [&](int g, float (&br)[U], float (&bt)[U],
                             float (&bb)[U], float (&bv)[U]) {
        const int base = (T_DIM - 2) - g * U;
#pragma unroll
        for (int u = 0; u < U; ++u) {
            const int idx = (base - u) * B_DIM + c;
            const float iw    = expf(bt[u] - bb[u]);
            const float rho_t = fminf(rho_clip, iw);
            const float cis_t = fminf(cis_clip, iw);
            out_rho[idx] = rho_t;
            const float gcis = GAMMA * cis_t;
            // rest = v_t + rho*(rew + g*v_next - v_t) - gcis*v_next  (carry-independent)
            const float rest = fmaf(rho_t, fmaf(GAMMA, v_next, br[u]) - bv[u], bv[u])
                               - gcis * v_next;
            const float vt = fmaf(gcis, carry, rest);   // single dependent FMA
            out_v[idx] = vt;
            carry  = vt;
            v_next = bv[u];
        }
    };

    // Group 127: slots u = 0..6 valid (t = 6-u), slot 7 is t = -1.
    auto load_group_last = [&](float (&br)[U], float (&bt)[U],
                               float (&bb)[U], float (&bv)[U]) {
#pragma unroll
        for (int u = 0; u < 7; ++u) {
            const int idx = (6 - u) * B_DIM + c;
            br[u] = rew[idx];
            bt[u] = tlp[idx];
            bb[u] = blp[idx];
            bv[u] = v[idx];
        }
    };

    auto compute_group_last = [&](float (&br)[U], float (&bt)[U],
                                  float (&bb)[U], float (&bv)[U]) {
#pragma unroll
        for (int u = 0; u < 7; ++u) {
            const int idx = (6 - u) * B_DIM + c;
            const float iw    = expf(bt[u] - bb[u]);
            const float rho_t = fminf(rho_clip, iw);
            const float cis_t = fminf(cis_clip, iw);
            out_rho[idx] = rho_t;
            const float gcis = GAMMA * cis_t;
            const float rest = fmaf(rho_t, fmaf(GAMMA, v_next, br[u]) - bv[u], bv[u])
                               - gcis * v_next;
            const float vt = fmaf(gcis, carry, rest);
            out_v[idx] = vt;
            carry  = vt;
            v_next = bv[u];
        }
    };

    // prologue: fill 4 buffers (groups 0..3, all valid)
    load_group(0, b0r, b0t, b0b, b0v);
    load_group(1, b1r, b1t, b1b, b1v);
    load_group(2, b2r, b2t, b2b, b2v);
    load_group(3, b3r, b3t, b3b, b3v);

    // main loop: groups 0..119 computed, 4..123 loaded — all branch-free
    for (int g = 0; g < 120; g += 4) {
        compute_group(g,     b0r, b0t, b0b, b0v);
        load_group(g + 4,    b0r, b0t, b0b, b0v);
        compute_group(g + 1, b1r, b1t, b1b, b1v);
        load_group(g + 5,    b1r, b1t, b1b, b1v);
        compute_group(g + 2, b2r, b2t, b2b, b2v);
        load_group(g + 6,    b2r, b2t, b2b, b2v);
        compute_group(g + 3, b3r, b3t, b3b, b3v);
        load_group(g + 7,    b3r, b3t, b3b, b3v);
    }

    // peeled iteration g = 120: loads 124..126 full, 127 guarded
    compute_group(120, b0r, b0t, b0b, b0v);
    load_group(124,    b0r, b0t, b0b, b0v);
    compute_group(121, b1r, b1t, b1b, b1v);
    load_group(125,    b1r, b1t, b1b, b1v);
    compute_group(122, b2r, b2t, b2b, b2v);
    load_group(126,    b2r, b2t, b2b, b2v);
    compute_group(123, b3r, b3t, b3b, b3v);
    load_group_last(   b3r, b3t, b3b, b3v);

    // epilogue: compute groups 124..127
    compute_group(124, b0r, b0t, b0b, b0v);
    compute_group(125, b1r, b1t, b1b, b1v);
    compute_group(126, b2r, b2t, b2b, b2v);
    compute_group_last(b3r, b3t, b3b, b3v);
}

extern "C" void kernel_launch(void* const* d_in, const int* in_sizes, int n_in,
                              void* d_out, int out_size, void* d_ws, size_t ws_size,
                              hipStream_t stream) {
    const float* v    = (const float*)d_in[0];   // target_value   (T,B)
    const float* rew  = (const float*)d_in[1];   // rewards        (T,B)
    const float* tlp  = (const float*)d_in[2];   // target_log_policy
    const float* blp  = (const float*)d_in[3];   // behaviour_log_policy
    const float* rho  = (const float*)d_in[4];   // scalar
    const float* cis  = (const float*)d_in[5];   // scalar

    float* out_v   = (float*)d_out;                                  // (T-1) x B
    float* out_rho = (float*)d_out + (size_t)(T_DIM - 1) * B_DIM;    // T x B

    dim3 grid(B_DIM / 64), block(64);
    vtrace_scan_kernel<<<grid, block, 0, stream>>>(v, rew, tlp, blp, rho, cis,
                                                   out_v, out_rho);
}

// Round 4
// 337.076 us; speedup vs baseline: 1.0101x; 1.0101x over previous
//
#include <hip/hip_runtime.h>

#define T_DIM 1024
#define B_DIM 16384
#define ROWB  65536          // B_DIM * 4 bytes
#define GAMMA 0.99f

// Manual software pipeline, depth D=10 rows, staged via global_load_lds
// (no dest VGPRs -> no register-recycling hazard). Exactly 6 vmem ops per
// body (2 asm stores + 4 global_load_lds), all order-pinned, so counted
// s_waitcnt vmcnt(K) is exact. Steady-state K = 6*(D-1) = 54; max 60 <= 63.

#define GL(arr, j, a)                                                      \
  __builtin_amdgcn_global_load_lds(                                        \
      (const __attribute__((address_space(1))) void*)((arr) + off_c),      \
      (__attribute__((address_space(3))) void*)&lds[j][a][0], 4, 0, 0)

#define PREF(j)                                                            \
  do {                                                                     \
    const int rp = (rowp >= 0) ? rowp : 0;        /* clamp tail rows */    \
    const size_t off_c = (size_t)rp * B_DIM + (size_t)c;                   \
    GL(rew, j, 0); GL(tlp, j, 1); GL(blp, j, 2); GL(vvp, j, 3);            \
    --rowp;                                                                \
  } while (0)

#define BODY(j, KW)                                                        \
  do {                                                                     \
    asm volatile("s_waitcnt vmcnt(" #KW ")" ::: "memory");                 \
    __builtin_amdgcn_sched_barrier(0);                                     \
    const float brw = lds[j][0][tid];                                      \
    const float btl = lds[j][1][tid];                                      \
    const float bbl = lds[j][2][tid];                                      \
    const float bvv = lds[j][3][tid];                                      \
    const float iw    = expf(btl - bbl);                                   \
    const float rho_t = fminf(rho_clip, iw);                               \
    const float cis_t = fminf(cis_clip, iw);                               \
    const float gcis  = GAMMA * cis_t;                                     \
    const float rest  = fmaf(rho_t, fmaf(GAMMA, v_next, brw) - bvv, bvv)   \
                        - gcis * v_next;                                   \
    const float vt    = fmaf(gcis, carry, rest);                           \
    asm volatile("global_store_dword %0, %1, %2"                           \
                 :: "v"(ofs_s), "v"(rho_t), "s"(orho));                    \
    asm volatile("global_store_dword %0, %1, %2"                           \
                 :: "v"(ofs_s), "v"(vt), "s"(ov));                         \
    carry  = vt;                                                           \
    v_next = bvv;                                                          \
    ofs_s -= ROWB;                                                         \
    asm volatile("s_waitcnt lgkmcnt(0)" ::: "memory"); /* WAR on slot */   \
    __builtin_amdgcn_sched_barrier(0);                                     \
    PREF(j);                                                               \
  } while (0)

__global__ __launch_bounds__(64, 1)
void vtrace_scan_kernel(const float* __restrict__ vvp,
                        const float* __restrict__ rew,
                        const float* __restrict__ tlp,
                        const float* __restrict__ blp,
                        const float* __restrict__ rho_p,
                        const float* __restrict__ cis_p,
                        float* __restrict__ ov,      // (T-1) x B
                        float* __restrict__ orho)    // T x B
{
    __shared__ float lds[10][4][64];                 // slot, array, lane (10 KB)
    const int tid = threadIdx.x;
    const int c   = blockIdx.x * 64 + tid;           // column, coalesced
    const float rho_clip = *rho_p;
    const float cis_clip = *cis_p;

    // Row 1023: rho store + scan seed (plain C, drained before asm region).
    {
        const size_t idx = (size_t)(T_DIM - 1) * B_DIM + c;
        const float iw = expf(tlp[idx] - blp[idx]);
        orho[idx] = fminf(rho_clip, iw);
    }
    float v_next = vvp[(size_t)(T_DIM - 1) * B_DIM + c];
    float carry  = v_next;

    // Fence: zero the vmcnt counter so manual counts are absolute.
    asm volatile("" :: "v"(v_next), "v"(rho_clip), "v"(cis_clip));
    asm volatile("s_waitcnt vmcnt(0)" ::: "memory");
    __builtin_amdgcn_sched_barrier(0);

    int rowp  = T_DIM - 2;                      // next prefetch row (1022)
    int ofs_s = (T_DIM - 2) * ROWB + c * 4;     // store byte offset, row 1022

    // Prologue: fill slots 0..9 with rows 1022..1013 (40 loads in flight).
    PREF(0); PREF(1); PREF(2); PREF(3); PREF(4);
    PREF(5); PREF(6); PREF(7); PREF(8); PREF(9);

    // Warm-up bodies i = 0..9: K = 36 + 2i.
    BODY(0, 36); BODY(1, 38); BODY(2, 40); BODY(3, 42); BODY(4, 44);
    BODY(5, 46); BODY(6, 48); BODY(7, 50); BODY(8, 52); BODY(9, 54);

    // Main loop: bodies 10..1019 (101 blocks of 10), steady-state K = 54.
    for (int blk = 0; blk < 101; ++blk) {
        BODY(0, 54); BODY(1, 54); BODY(2, 54); BODY(3, 54); BODY(4, 54);
        BODY(5, 54); BODY(6, 54); BODY(7, 54); BODY(8, 54); BODY(9, 54);
    }

    // Tail bodies 1020..1022 (rows 2,1,0); their prefetches are row-0-clamped.
    BODY(0, 54); BODY(1, 54); BODY(2, 54);
}

extern "C" void kernel_launch(void* const* d_in, const int* in_sizes, int n_in,
                              void* d_out, int out_size, void* d_ws, size_t ws_size,
                              hipStream_t stream) {
    const float* v    = (const float*)d_in[0];   // target_value   (T,B)
    const float* rew  = (const float*)d_in[1];   // rewards        (T,B)
    const float* tlp  = (const float*)d_in[2];   // target_log_policy
    const float* blp  = (const float*)d_in[3];   // behaviour_log_policy
    const float* rho  = (const float*)d_in[4];   // scalar
    const float* cis  = (const float*)d_in[5];   // scalar

    float* out_v   = (float*)d_out;                                  // (T-1) x B
    float* out_rho = (float*)d_out + (size_t)(T_DIM - 1) * B_DIM;    // T x B

    dim3 grid(B_DIM / 64), block(64);
    vtrace_scan_kernel<<<grid, block, 0, stream>>>(v, rew, tlp, blp, rho, cis,
                                                   out_v, out_rho);
}